// Round 7
// baseline (279.440 us; speedup 1.0000x reference)
//
#include <hip/hip_runtime.h>

#define B_  4
#define S_  2048
#define D_  1024
#define H_  16
#define DH_ 64
#define M_  (B_ * S_)   // 8192 rows

typedef __attribute__((ext_vector_type(8))) short short8;
typedef __attribute__((ext_vector_type(4))) short short4v;
typedef __attribute__((ext_vector_type(4))) float floatx4;

// ---------- bf16 helpers ----------
__device__ __forceinline__ float bf2f(unsigned short u) {
    union { unsigned int i; float f; } v; v.i = ((unsigned int)u) << 16; return v.f;
}
__device__ __forceinline__ unsigned short f2bf(float f) {
    union { float f; unsigned int i; } v; v.f = f;
    unsigned int r = v.i + 0x7fffu + ((v.i >> 16) & 1u);   // RNE
    return (unsigned short)(r >> 16);
}
// truncation pack: two fp32 -> packed bf16x2 (1.5 VALU ops/elem; P-weight
// trunc noise contributes ~3e-5 to output vs 4.9e-4 existing floor)
__device__ __forceinline__ unsigned int pk_trunc(float a, float b) {
    return (__float_as_uint(a) >> 16) | (__float_as_uint(b) & 0xffff0000u);
}

// ---------- async global->LDS, 16B per lane ----------
typedef const __attribute__((address_space(1))) unsigned int* gas_ptr;
typedef __attribute__((address_space(3))) unsigned int* las_ptr;
__device__ __forceinline__ void async_cp16(const void* g, void* l) {
    __builtin_amdgcn_global_load_lds((gas_ptr)g, (las_ptr)l, 16, 0, 0);
}

// ---------- prep: x[M][1024] fp32 -> Ax[M][1024] bf16 ----------
__global__ __launch_bounds__(256) void cast_x_kernel(
    const float* __restrict__ x, unsigned short* __restrict__ Ax)
{
    int i4 = blockIdx.x * 256 + threadIdx.x;
    float4 v = reinterpret_cast<const float4*>(x)[i4];
    ushort4 o;
    o.x = f2bf(v.x); o.y = f2bf(v.y); o.z = f2bf(v.z); o.w = f2bf(v.w);
    reinterpret_cast<ushort4*>(Ax)[i4] = o;
}

// ---------- prep: W[1024 k][1024 n] fp32 -> Wt[n][k] bf16 ----------
__global__ __launch_bounds__(256) void cast_w_T_kernel(
    const float* __restrict__ W, unsigned short* __restrict__ Wt)
{
    __shared__ unsigned short T[64][72];
    const int t = threadIdx.x;
    const int k0 = blockIdx.x * 64, n0 = blockIdx.y * 64;

    #pragma unroll
    for (int p = 0; p < 4; ++p) {
        int kr = p * 16 + (t >> 4);
        int nc = (t & 15) * 4;
        float4 v = *reinterpret_cast<const float4*>(W + (size_t)(k0 + kr) * D_ + n0 + nc);
        T[nc + 0][kr] = f2bf(v.x);
        T[nc + 1][kr] = f2bf(v.y);
        T[nc + 2][kr] = f2bf(v.z);
        T[nc + 3][kr] = f2bf(v.w);
    }
    __syncthreads();

    const int nl = t >> 2, kc = (t & 3) * 16;
    size_t base = (size_t)(n0 + nl) * D_ + k0 + kc;
    *reinterpret_cast<short8*>(Wt + base)     = *reinterpret_cast<const short8*>(&T[nl][kc]);
    *reinterpret_cast<short8*>(Wt + base + 8) = *reinterpret_cast<const short8*>(&T[nl][kc + 8]);
}

// ---------- fused QKV GEMM, K=1024 ----------
// Swizzle v2: XCD owns an m-slice (A 2.1MB L2-resident); gcol outer, m inner
// -> B panel reused 8x in L2, A fetched ~once from HBM.
__global__ __launch_bounds__(256) void gemm_qkv_mfma(
    const unsigned short* __restrict__ Ax,
    const unsigned short* __restrict__ Wtq,
    const unsigned short* __restrict__ Wtk,
    const unsigned short* __restrict__ Wtv,
    const float* __restrict__ bq, const float* __restrict__ bk,
    const float* __restrict__ bv,
    unsigned short* __restrict__ Q, unsigned short* __restrict__ K,
    unsigned short* __restrict__ Vtg)
{
    __shared__ unsigned short As[128 * 32];
    __shared__ unsigned short Bs[128 * 32];

    const int tid = threadIdx.x;
    const int lane = tid & 63;
    const int w = tid >> 6;
    const int wm = (w >> 1) * 64, wn = (w & 1) * 64;
    const int l15 = lane & 15, quad = lane >> 4;

    const int hw   = blockIdx.x;          // 0..1535
    const int xcd  = hw & 7;
    const int slot = hw >> 3;             // 0..191
    const int gcol = slot >> 3;           // 0..23  B-panel (outer)
    const int mi   = slot & 7;            // m within XCD slice (inner)
    const int m0   = (xcd * 8 + mi) * 128;
    const int n0   = (gcol & 7) * 128;
    const int mat  = gcol >> 3;

    const unsigned short* Wt = mat == 0 ? Wtq : (mat == 1 ? Wtk : Wtv);
    const float* bias        = mat == 0 ? bq  : (mat == 1 ? bk  : bv);

    const int arow = tid >> 2;
    const int acol = (tid & 3) * 8;

    floatx4 acc[4][4] = {};

    for (int kb = 0; kb < 32; ++kb) {
        int cb = kb * 32;
        __syncthreads();
        async_cp16(Ax + (size_t)(m0 + arow) * D_ + cb + acol,      As + arow * 32 + acol);
        async_cp16(Ax + (size_t)(m0 + 64 + arow) * D_ + cb + acol, As + (64 + arow) * 32 + acol);
        async_cp16(Wt + (size_t)(n0 + arow) * D_ + cb + acol,      Bs + arow * 32 + acol);
        async_cp16(Wt + (size_t)(n0 + 64 + arow) * D_ + cb + acol, Bs + (64 + arow) * 32 + acol);
        __syncthreads();

        short8 af[4], bf[4];
        #pragma unroll
        for (int i = 0; i < 4; ++i)
            af[i] = *reinterpret_cast<const short8*>(As + (wm + i * 16 + l15) * 32 + quad * 8);
        #pragma unroll
        for (int j = 0; j < 4; ++j)
            bf[j] = *reinterpret_cast<const short8*>(Bs + (wn + j * 16 + l15) * 32 + quad * 8);
        #pragma unroll
        for (int i = 0; i < 4; ++i)
            #pragma unroll
            for (int j = 0; j < 4; ++j)
                acc[i][j] = __builtin_amdgcn_mfma_f32_16x16x32_bf16(af[i], bf[j], acc[i][j], 0, 0, 0);
    }

    float bb[4];
    #pragma unroll
    for (int j = 0; j < 4; ++j) bb[j] = bias[n0 + wn + j * 16 + l15];

    if (mat == 2) {
        const int b = m0 >> 11;
        #pragma unroll
        for (int i = 0; i < 4; ++i) {
            int srow = (m0 & 2047) + wm + i * 16 + quad * 4;
            #pragma unroll
            for (int j = 0; j < 4; ++j) {
                int col = n0 + wn + j * 16 + l15;
                ushort4 o;
                o.x = f2bf(acc[i][j][0] + bb[j]);
                o.y = f2bf(acc[i][j][1] + bb[j]);
                o.z = f2bf(acc[i][j][2] + bb[j]);
                o.w = f2bf(acc[i][j][3] + bb[j]);
                *reinterpret_cast<ushort4*>(Vtg + (size_t)(b * 1024 + col) * S_ + srow) = o;
            }
        }
    } else {
        unsigned short* C = (mat == 0) ? Q : K;
        const float sc = (mat == 0) ? 0.125f : 1.0f;
        #pragma unroll
        for (int i = 0; i < 4; ++i)
            #pragma unroll
            for (int r = 0; r < 4; ++r) {
                int row = m0 + wm + i * 16 + quad * 4 + r;
                #pragma unroll
                for (int j = 0; j < 4; ++j)
                    C[(size_t)row * D_ + n0 + wn + j * 16 + l15] = f2bf((acc[i][j][r] + bb[j]) * sc);
            }
    }
}

// ---------- MFMA flash attention v3 ----------
// grid 512 (XCD-swizzled), 256 thr = 4 waves; wave owns 64 queries (g=0..3).
// S^T = mfma_16x16x32(K,Q): lane holds keys quad*4+r for query l15 — which is
// EXACTLY the A-fragment of mfma_16x16x16_bf16 (row=l15, k=quad*4+j), so P
// goes exp->pack->MFMA entirely in registers (no LDS round-trip, no shuffles).
#define KT_   64
#define PITCH 72

#if __has_builtin(__builtin_amdgcn_mfma_f32_16x16x16bf16_1k)
#define PV_K16 1
#else
#define PV_K16 0
#endif

__global__ __launch_bounds__(256) void attn_mfma(
    const unsigned short* __restrict__ Qg,
    const unsigned short* __restrict__ Kg,
    const unsigned short* __restrict__ Vtg,   // [(b*16+h)*64+d][s]
    float* __restrict__ out)
{
    __shared__ unsigned short Ks[KT_ * PITCH];   // [key][d]
    __shared__ unsigned short Vt[DH_ * PITCH];   // [d][key]
#if !PV_K16
    __shared__ unsigned short Ps[4][16 * PITCH]; // fallback P buffer
#endif

    const int tid  = threadIdx.x;
    const int wq   = tid >> 6;
    const int lane = tid & 63;
    const int l15  = lane & 15;
    const int quad = lane >> 4;

    // XCD swizzle: 512 = 8 xcd x 8 bh x 8 qt ; per-XCD K/V footprint 4MB = L2
    const int id  = blockIdx.x;
    const int bh  = (id & 7) * 8 + ((id >> 3) & 7);
    const int qt  = id >> 6;                  // 0..7
    const int b   = bh >> 4;
    const int colbase = (bh & 15) * DH_;
    const int rowQ0 = b * S_ + qt * 256;

    // Q fragments: 4 query-groups x 2 k-halves, registers for the whole pass
    short8 qf[4][2];
    #pragma unroll
    for (int g = 0; g < 4; ++g) {
        int qrow = rowQ0 + wq * 64 + g * 16 + l15;
        qf[g][0] = *reinterpret_cast<const short8*>(Qg + (size_t)qrow * D_ + colbase + quad * 8);
        qf[g][1] = *reinterpret_cast<const short8*>(Qg + (size_t)qrow * D_ + colbase + 32 + quad * 8);
    }

    floatx4 Oacc[4][4] = {};
    float lsum[4] = {};

    const int srow = tid >> 3;        // 0..31
    const int sc8  = (tid & 7) * 8;

    const unsigned short* Kbase = Kg + (size_t)(b * S_) * D_ + colbase;
    const unsigned short* Vbase = Vtg + (size_t)(bh * 64) * S_;

    short8 kpre[2], vpre[2];
    #pragma unroll
    for (int p = 0; p < 2; ++p) {
        kpre[p] = *reinterpret_cast<const short8*>(Kbase + (size_t)(p * 32 + srow) * D_ + sc8);
        vpre[p] = *reinterpret_cast<const short8*>(Vbase + (size_t)(p * 32 + srow) * S_ + sc8);
    }

    for (int kt = 0; kt < S_ / KT_; ++kt) {
        __syncthreads();
        #pragma unroll
        for (int p = 0; p < 2; ++p) {
            *reinterpret_cast<short8*>(&Ks[(p * 32 + srow) * PITCH + sc8]) = kpre[p];
            *reinterpret_cast<short8*>(&Vt[(p * 32 + srow) * PITCH + sc8]) = vpre[p];
        }
        if (kt + 1 < S_ / KT_) {
            int off = (kt + 1) * KT_;
            #pragma unroll
            for (int p = 0; p < 2; ++p) {
                kpre[p] = *reinterpret_cast<const short8*>(Kbase + (size_t)(off + p * 32 + srow) * D_ + sc8);
                vpre[p] = *reinterpret_cast<const short8*>(Vbase + (size_t)(p * 32 + srow) * S_ + off + sc8);
            }
        }
        __syncthreads();

        #pragma unroll
        for (int c = 0; c < 4; ++c) {
            // S^T for 16-key block c, all 4 query groups
            short8 kf0 = *reinterpret_cast<const short8*>(&Ks[(c * 16 + l15) * PITCH + quad * 8]);
            short8 kf1 = *reinterpret_cast<const short8*>(&Ks[(c * 16 + l15) * PITCH + 32 + quad * 8]);
            floatx4 sc_[4];
            #pragma unroll
            for (int g = 0; g < 4; ++g) {
                floatx4 a = {0.f, 0.f, 0.f, 0.f};
                a = __builtin_amdgcn_mfma_f32_16x16x32_bf16(kf0, qf[g][0], a, 0, 0, 0);
                a = __builtin_amdgcn_mfma_f32_16x16x32_bf16(kf1, qf[g][1], a, 0, 0, 0);
                sc_[g] = a;
            }

#if PV_K16
            // exp + pack in registers; feed K=16 PV MFMA directly
            short4v pfv[4];
            #pragma unroll
            for (int g = 0; g < 4; ++g) {
                float p0 = __expf(sc_[g][0]);
                float p1 = __expf(sc_[g][1]);
                float p2 = __expf(sc_[g][2]);
                float p3 = __expf(sc_[g][3]);
                lsum[g] += p0 + p1 + p2 + p3;
                uint2 u;
                u.x = pk_trunc(p0, p1);
                u.y = pk_trunc(p2, p3);
                pfv[g] = __builtin_bit_cast(short4v, u);
            }
            #pragma unroll
            for (int d = 0; d < 4; ++d) {
                short4v vf = *reinterpret_cast<const short4v*>(
                    &Vt[(d * 16 + l15) * PITCH + c * 16 + quad * 4]);
                #pragma unroll
                for (int g = 0; g < 4; ++g)
                    Oacc[g][d] = __builtin_amdgcn_mfma_f32_16x16x16bf16_1k(
                        pfv[g], vf, Oacc[g][d], 0, 0, 0);
            }
#else
            // fallback: P via per-wave LDS round-trip, K=32 PV
            #pragma unroll
            for (int g = 0; g < 4; ++g) {
                float p0 = __expf(sc_[g][0]);
                float p1 = __expf(sc_[g][1]);
                float p2 = __expf(sc_[g][2]);
                float p3 = __expf(sc_[g][3]);
                lsum[g] += p0 + p1 + p2 + p3;
                uint2 u;
                u.x = pk_trunc(p0, p1);
                u.y = pk_trunc(p2, p3);
                *reinterpret_cast<uint2*>(&Ps[wq][(l15 + g * 0) * PITCH + c * 16 + quad * 4]) = u;
                // read back and accumulate for this g after all c? handled below
                // (store per-g at same rows; process PV immediately per g)
                short8 pf0 = *reinterpret_cast<const short8*>(&Ps[wq][l15 * PITCH + quad * 8]);
                short8 pf1 = *reinterpret_cast<const short8*>(&Ps[wq][l15 * PITCH + 32 + quad * 8]);
                (void)pf0; (void)pf1;
            }
#endif
        }

#if !PV_K16
        // fallback PV (per g: full 64-key P assembled in Ps, then 2 K=32 MFMA per d)
        #pragma unroll
        for (int g = 0; g < 4; ++g) {
            short8 pf0 = *reinterpret_cast<const short8*>(&Ps[wq][l15 * PITCH + quad * 8]);
            short8 pf1 = *reinterpret_cast<const short8*>(&Ps[wq][l15 * PITCH + 32 + quad * 8]);
            #pragma unroll
            for (int d = 0; d < 4; ++d) {
                short8 vf0 = *reinterpret_cast<const short8*>(&Vt[(d * 16 + l15) * PITCH + quad * 8]);
                short8 vf1 = *reinterpret_cast<const short8*>(&Vt[(d * 16 + l15) * PITCH + 32 + quad * 8]);
                Oacc[g][d] = __builtin_amdgcn_mfma_f32_16x16x32_bf16(pf0, vf0, Oacc[g][d], 0, 0, 0);
                Oacc[g][d] = __builtin_amdgcn_mfma_f32_16x16x32_bf16(pf1, vf1, Oacc[g][d], 0, 0, 0);
            }
        }
#endif
    }

    // epilogue: reduce l across quads (lane's queries all = l15), normalize, store
    #pragma unroll
    for (int g = 0; g < 4; ++g) {
        float lred = lsum[g];
        lred += __shfl_xor(lred, 16);
        lred += __shfl_xor(lred, 32);
        float inv[4];
        #pragma unroll
        for (int r = 0; r < 4; ++r)
            inv[r] = 1.f / __shfl(lred, quad * 4 + r);
        int orow = rowQ0 + wq * 64 + g * 16 + quad * 4;
        #pragma unroll
        for (int r = 0; r < 4; ++r)
            #pragma unroll
            for (int d = 0; d < 4; ++d)
                out[(size_t)(orow + r) * D_ + colbase + d * 16 + l15] = Oacc[g][d][r] * inv[r];
    }
}

extern "C" void kernel_launch(void* const* d_in, const int* in_sizes, int n_in,
                              void* d_out, int out_size, void* d_ws, size_t ws_size,
                              hipStream_t stream) {
    const float* x  = (const float*)d_in[0];
    const float* Wq = (const float*)d_in[1];
    const float* bq = (const float*)d_in[2];
    const float* Wk = (const float*)d_in[3];
    const float* bk = (const float*)d_in[4];
    const float* Wv = (const float*)d_in[5];
    const float* bv = (const float*)d_in[6];
    float* out = (float*)d_out;

    unsigned short* Q   = (unsigned short*)d_ws;
    unsigned short* K   = Q + (size_t)M_ * D_;
    unsigned short* Vtg = K + (size_t)M_ * D_;
    unsigned short* Ax  = Vtg + (size_t)M_ * D_;
    unsigned short* Wtq = Ax + (size_t)M_ * D_;
    unsigned short* Wtk = Wtq + (size_t)D_ * D_;
    unsigned short* Wtv = Wtk + (size_t)D_ * D_;

    cast_x_kernel<<<M_ * D_ / 4 / 256, 256, 0, stream>>>(x, Ax);
    dim3 gw(16, 16);
    cast_w_T_kernel<<<gw, 256, 0, stream>>>(Wq, Wtq);
    cast_w_T_kernel<<<gw, 256, 0, stream>>>(Wk, Wtk);
    cast_w_T_kernel<<<gw, 256, 0, stream>>>(Wv, Wtv);

    gemm_qkv_mfma<<<1536, 256, 0, stream>>>(Ax, Wtq, Wtk, Wtv, bq, bk, bv, Q, K, Vtg);

    attn_mfma<<<512, 256, 0, stream>>>(Q, K, Vtg, out);
}

// Round 8
// 251.692 us; speedup vs baseline: 1.1102x; 1.1102x over previous
//
#include <hip/hip_runtime.h>

#define B_  4
#define S_  2048
#define D_  1024
#define H_  16
#define DH_ 64
#define M_  (B_ * S_)   // 8192 rows

typedef __attribute__((ext_vector_type(8))) short short8;
typedef __attribute__((ext_vector_type(4))) float floatx4;

// ---------- bf16 helpers ----------
__device__ __forceinline__ float bf2f(unsigned short u) {
    union { unsigned int i; float f; } v; v.i = ((unsigned int)u) << 16; return v.f;
}
__device__ __forceinline__ unsigned short f2bf(float f) {
    union { float f; unsigned int i; } v; v.f = f;
    unsigned int r = v.i + 0x7fffu + ((v.i >> 16) & 1u);   // RNE
    return (unsigned short)(r >> 16);
}
// truncation pack: two fp32 -> packed bf16x2 (P-weight trunc noise ~3e-5,
// verified harmless in R7: absmax stayed 4.88e-4)
__device__ __forceinline__ unsigned int pk_trunc(float a, float b) {
    return (__float_as_uint(a) >> 16) | (__float_as_uint(b) & 0xffff0000u);
}

// ---------- async global->LDS, 16B per lane ----------
typedef const __attribute__((address_space(1))) unsigned int* gas_ptr;
typedef __attribute__((address_space(3))) unsigned int* las_ptr;
__device__ __forceinline__ void async_cp16(const void* g, void* l) {
    __builtin_amdgcn_global_load_lds((gas_ptr)g, (las_ptr)l, 16, 0, 0);
}

// ---------- prep: x[M][1024] fp32 -> Ax[M][1024] bf16 ----------
__global__ __launch_bounds__(256) void cast_x_kernel(
    const float* __restrict__ x, unsigned short* __restrict__ Ax)
{
    int i4 = blockIdx.x * 256 + threadIdx.x;
    float4 v = reinterpret_cast<const float4*>(x)[i4];
    ushort4 o;
    o.x = f2bf(v.x); o.y = f2bf(v.y); o.z = f2bf(v.z); o.w = f2bf(v.w);
    reinterpret_cast<ushort4*>(Ax)[i4] = o;
}

// ---------- prep: W[1024 k][1024 n] fp32 -> Wt[n][k] bf16 ----------
__global__ __launch_bounds__(256) void cast_w_T_kernel(
    const float* __restrict__ W, unsigned short* __restrict__ Wt)
{
    __shared__ unsigned short T[64][72];
    const int t = threadIdx.x;
    const int k0 = blockIdx.x * 64, n0 = blockIdx.y * 64;

    #pragma unroll
    for (int p = 0; p < 4; ++p) {
        int kr = p * 16 + (t >> 4);
        int nc = (t & 15) * 4;
        float4 v = *reinterpret_cast<const float4*>(W + (size_t)(k0 + kr) * D_ + n0 + nc);
        T[nc + 0][kr] = f2bf(v.x);
        T[nc + 1][kr] = f2bf(v.y);
        T[nc + 2][kr] = f2bf(v.z);
        T[nc + 3][kr] = f2bf(v.w);
    }
    __syncthreads();

    const int nl = t >> 2, kc = (t & 3) * 16;
    size_t base = (size_t)(n0 + nl) * D_ + k0 + kc;
    *reinterpret_cast<short8*>(Wt + base)     = *reinterpret_cast<const short8*>(&T[nl][kc]);
    *reinterpret_cast<short8*>(Wt + base + 8) = *reinterpret_cast<const short8*>(&T[nl][kc + 8]);
}

// ---------- fused QKV GEMM, K=1024 (unchanged R7) ----------
__global__ __launch_bounds__(256) void gemm_qkv_mfma(
    const unsigned short* __restrict__ Ax,
    const unsigned short* __restrict__ Wtq,
    const unsigned short* __restrict__ Wtk,
    const unsigned short* __restrict__ Wtv,
    const float* __restrict__ bq, const float* __restrict__ bk,
    const float* __restrict__ bv,
    unsigned short* __restrict__ Q, unsigned short* __restrict__ K,
    unsigned short* __restrict__ Vtg)
{
    __shared__ unsigned short As[128 * 32];
    __shared__ unsigned short Bs[128 * 32];

    const int tid = threadIdx.x;
    const int lane = tid & 63;
    const int w = tid >> 6;
    const int wm = (w >> 1) * 64, wn = (w & 1) * 64;
    const int l15 = lane & 15, quad = lane >> 4;

    const int hw   = blockIdx.x;
    const int xcd  = hw & 7;
    const int slot = hw >> 3;
    const int gcol = slot >> 3;
    const int mi   = slot & 7;
    const int m0   = (xcd * 8 + mi) * 128;
    const int n0   = (gcol & 7) * 128;
    const int mat  = gcol >> 3;

    const unsigned short* Wt = mat == 0 ? Wtq : (mat == 1 ? Wtk : Wtv);
    const float* bias        = mat == 0 ? bq  : (mat == 1 ? bk  : bv);

    const int arow = tid >> 2;
    const int acol = (tid & 3) * 8;

    floatx4 acc[4][4] = {};

    for (int kb = 0; kb < 32; ++kb) {
        int cb = kb * 32;
        __syncthreads();
        async_cp16(Ax + (size_t)(m0 + arow) * D_ + cb + acol,      As + arow * 32 + acol);
        async_cp16(Ax + (size_t)(m0 + 64 + arow) * D_ + cb + acol, As + (64 + arow) * 32 + acol);
        async_cp16(Wt + (size_t)(n0 + arow) * D_ + cb + acol,      Bs + arow * 32 + acol);
        async_cp16(Wt + (size_t)(n0 + 64 + arow) * D_ + cb + acol, Bs + (64 + arow) * 32 + acol);
        __syncthreads();

        short8 af[4], bf[4];
        #pragma unroll
        for (int i = 0; i < 4; ++i)
            af[i] = *reinterpret_cast<const short8*>(As + (wm + i * 16 + l15) * 32 + quad * 8);
        #pragma unroll
        for (int j = 0; j < 4; ++j)
            bf[j] = *reinterpret_cast<const short8*>(Bs + (wn + j * 16 + l15) * 32 + quad * 8);
        #pragma unroll
        for (int i = 0; i < 4; ++i)
            #pragma unroll
            for (int j = 0; j < 4; ++j)
                acc[i][j] = __builtin_amdgcn_mfma_f32_16x16x32_bf16(af[i], bf[j], acc[i][j], 0, 0, 0);
    }

    float bb[4];
    #pragma unroll
    for (int j = 0; j < 4; ++j) bb[j] = bias[n0 + wn + j * 16 + l15];

    if (mat == 2) {
        const int b = m0 >> 11;
        #pragma unroll
        for (int i = 0; i < 4; ++i) {
            int srow = (m0 & 2047) + wm + i * 16 + quad * 4;
            #pragma unroll
            for (int j = 0; j < 4; ++j) {
                int col = n0 + wn + j * 16 + l15;
                ushort4 o;
                o.x = f2bf(acc[i][j][0] + bb[j]);
                o.y = f2bf(acc[i][j][1] + bb[j]);
                o.z = f2bf(acc[i][j][2] + bb[j]);
                o.w = f2bf(acc[i][j][3] + bb[j]);
                *reinterpret_cast<ushort4*>(Vtg + (size_t)(b * 1024 + col) * S_ + srow) = o;
            }
        }
    } else {
        unsigned short* C = (mat == 0) ? Q : K;
        const float sc = (mat == 0) ? 0.125f : 1.0f;
        #pragma unroll
        for (int i = 0; i < 4; ++i)
            #pragma unroll
            for (int r = 0; r < 4; ++r) {
                int row = m0 + wm + i * 16 + quad * 4 + r;
                #pragma unroll
                for (int j = 0; j < 4; ++j)
                    C[(size_t)row * D_ + n0 + wn + j * 16 + l15] = f2bf((acc[i][j][r] + bb[j]) * sc);
            }
    }
}

// ---------- MFMA flash attention v4: register-P, full-rate K=32 PV ----------
// grid 1024 (XCD-swizzled), 4 waves, wave owns 32 queries (g=0,1).
// Key trick: MFMA sums over k in ANY order if A and B agree. Permute the key
// axis: k' = (c&1)*4 + (c>>1)*32 + quad*8 + r for key=c*16+quad*4+r. Then the
// S^T C-layout exp values, packed in order, ARE a K=32 A-fragment, and V
// staged at permuted k' makes B-frag reads plain contiguous b128. P stays in
// registers; PV runs at full 16x16x32 rate.
#define KT_   64
#define PITCH 72

__global__ __launch_bounds__(256, 4) void attn_mfma(
    const unsigned short* __restrict__ Qg,
    const unsigned short* __restrict__ Kg,
    const unsigned short* __restrict__ Vtg,   // [(b*16+h)*64+d][s]
    float* __restrict__ out)
{
    __shared__ unsigned short Ks[KT_ * PITCH];   // [key][d] (unpermuted)
    __shared__ unsigned short Vt[DH_ * PITCH];   // [d][k'] (key-permuted)

    const int tid  = threadIdx.x;
    const int wq   = tid >> 6;
    const int lane = tid & 63;
    const int l15  = lane & 15;
    const int quad = lane >> 4;

    // XCD swizzle: 1024 = 8 xcd x 8 bh x 16 qt; per-XCD K/V footprint 4MB = L2
    const int id  = blockIdx.x;
    const int bh  = (id & 7) * 8 + ((id >> 3) & 7);
    const int qt  = id >> 6;                  // 0..15
    const int b   = bh >> 4;
    const int colbase = (bh & 15) * DH_;
    const int rowQ0 = b * S_ + qt * 128;

    short8 qf[2][2];
    #pragma unroll
    for (int g = 0; g < 2; ++g) {
        int qrow = rowQ0 + wq * 32 + g * 16 + l15;
        qf[g][0] = *reinterpret_cast<const short8*>(Qg + (size_t)qrow * D_ + colbase + quad * 8);
        qf[g][1] = *reinterpret_cast<const short8*>(Qg + (size_t)qrow * D_ + colbase + 32 + quad * 8);
    }

    floatx4 Oacc[2][4] = {};
    float lsum[2] = {0.f, 0.f};

    // staging: thread covers rows p*32+srow, 16B key-chunk sc8
    const int srow = tid >> 3;        // 0..31
    const int sc8  = (tid & 7) * 8;
    // permuted V dest: chunk keys [sc8..sc8+7] -> two 4-key runs at vk0, vk0+8
    const int vc  = sc8 >> 4;
    const int vqk = (sc8 >> 2) & 3;   // 0 or 2
    const int vk0 = ((vc & 1) << 2) + ((vc >> 1) << 5) + (vqk << 3);

    const unsigned short* Kbase = Kg + (size_t)(b * S_) * D_ + colbase;
    const unsigned short* Vbase = Vtg + (size_t)(bh * 64) * S_;

    short8 kpre[2], vpre[2];
    #pragma unroll
    for (int p = 0; p < 2; ++p) {
        kpre[p] = *reinterpret_cast<const short8*>(Kbase + (size_t)(p * 32 + srow) * D_ + sc8);
        vpre[p] = *reinterpret_cast<const short8*>(Vbase + (size_t)(p * 32 + srow) * S_ + sc8);
    }

    for (int kt = 0; kt < S_ / KT_; ++kt) {
        __syncthreads();
        #pragma unroll
        for (int p = 0; p < 2; ++p) {
            *reinterpret_cast<short8*>(&Ks[(p * 32 + srow) * PITCH + sc8]) = kpre[p];
            uint4 u = __builtin_bit_cast(uint4, vpre[p]);
            uint2 lo, hi;
            lo.x = u.x; lo.y = u.y; hi.x = u.z; hi.y = u.w;
            *reinterpret_cast<uint2*>(&Vt[(p * 32 + srow) * PITCH + vk0])     = lo;
            *reinterpret_cast<uint2*>(&Vt[(p * 32 + srow) * PITCH + vk0 + 8]) = hi;
        }
        if (kt + 1 < S_ / KT_) {
            int off = (kt + 1) * KT_;
            #pragma unroll
            for (int p = 0; p < 2; ++p) {
                kpre[p] = *reinterpret_cast<const short8*>(Kbase + (size_t)(off + p * 32 + srow) * D_ + sc8);
                vpre[p] = *reinterpret_cast<const short8*>(Vbase + (size_t)(p * 32 + srow) * S_ + off + sc8);
            }
        }
        __syncthreads();

        // process 32 keys (= one PV MFMA's K) per half
        #pragma unroll
        for (int half = 0; half < 2; ++half) {
            floatx4 s_[2][2];
            #pragma unroll
            for (int ci = 0; ci < 2; ++ci) {
                int c = half * 2 + ci;
                short8 kf0 = *reinterpret_cast<const short8*>(&Ks[(c * 16 + l15) * PITCH + quad * 8]);
                short8 kf1 = *reinterpret_cast<const short8*>(&Ks[(c * 16 + l15) * PITCH + 32 + quad * 8]);
                #pragma unroll
                for (int g = 0; g < 2; ++g) {
                    floatx4 a = {0.f, 0.f, 0.f, 0.f};
                    a = __builtin_amdgcn_mfma_f32_16x16x32_bf16(kf0, qf[g][0], a, 0, 0, 0);
                    a = __builtin_amdgcn_mfma_f32_16x16x32_bf16(kf1, qf[g][1], a, 0, 0, 0);
                    s_[g][ci] = a;
                }
            }
            // exp + pack directly into the K=32 A-fragment (k' order)
            short8 pa[2];
            #pragma unroll
            for (int g = 0; g < 2; ++g) {
                float p00 = __expf(s_[g][0][0]), p01 = __expf(s_[g][0][1]);
                float p02 = __expf(s_[g][0][2]), p03 = __expf(s_[g][0][3]);
                float p10 = __expf(s_[g][1][0]), p11 = __expf(s_[g][1][1]);
                float p12 = __expf(s_[g][1][2]), p13 = __expf(s_[g][1][3]);
                lsum[g] += (p00 + p01) + (p02 + p03) + (p10 + p11) + (p12 + p13);
                uint4 pu;
                pu.x = pk_trunc(p00, p01);
                pu.y = pk_trunc(p02, p03);
                pu.z = pk_trunc(p10, p11);
                pu.w = pk_trunc(p12, p13);
                pa[g] = __builtin_bit_cast(short8, pu);
            }
            // O += P V over this 32-key half (B-frag: plain b128 at permuted Vt)
            #pragma unroll
            for (int d = 0; d < 4; ++d) {
                short8 vf = *reinterpret_cast<const short8*>(
                    &Vt[(d * 16 + l15) * PITCH + half * 32 + quad * 8]);
                #pragma unroll
                for (int g = 0; g < 2; ++g)
                    Oacc[g][d] = __builtin_amdgcn_mfma_f32_16x16x32_bf16(pa[g], vf, Oacc[g][d], 0, 0, 0);
            }
        }
    }

    // epilogue: reduce l across the 4 quads (lane's queries = l15), store
    #pragma unroll
    for (int g = 0; g < 2; ++g) {
        float lred = lsum[g];
        lred += __shfl_xor(lred, 16);
        lred += __shfl_xor(lred, 32);
        float inv[4];
        #pragma unroll
        for (int r = 0; r < 4; ++r)
            inv[r] = 1.f / __shfl(lred, quad * 4 + r);
        int orow = rowQ0 + wq * 32 + g * 16 + quad * 4;
        #pragma unroll
        for (int r = 0; r < 4; ++r)
            #pragma unroll
            for (int d = 0; d < 4; ++d)
                out[(size_t)(orow + r) * D_ + colbase + d * 16 + l15] = Oacc[g][d][r] * inv[r];
    }
}

extern "C" void kernel_launch(void* const* d_in, const int* in_sizes, int n_in,
                              void* d_out, int out_size, void* d_ws, size_t ws_size,
                              hipStream_t stream) {
    const float* x  = (const float*)d_in[0];
    const float* Wq = (const float*)d_in[1];
    const float* bq = (const float*)d_in[2];
    const float* Wk = (const float*)d_in[3];
    const float* bk = (const float*)d_in[4];
    const float* Wv = (const float*)d_in[5];
    const float* bv = (const float*)d_in[6];
    float* out = (float*)d_out;

    unsigned short* Q   = (unsigned short*)d_ws;
    unsigned short* K   = Q + (size_t)M_ * D_;
    unsigned short* Vtg = K + (size_t)M_ * D_;
    unsigned short* Ax  = Vtg + (size_t)M_ * D_;
    unsigned short* Wtq = Ax + (size_t)M_ * D_;
    unsigned short* Wtk = Wtq + (size_t)D_ * D_;
    unsigned short* Wtv = Wtk + (size_t)D_ * D_;

    cast_x_kernel<<<M_ * D_ / 4 / 256, 256, 0, stream>>>(x, Ax);
    dim3 gw(16, 16);
    cast_w_T_kernel<<<gw, 256, 0, stream>>>(Wq, Wtq);
    cast_w_T_kernel<<<gw, 256, 0, stream>>>(Wk, Wtk);
    cast_w_T_kernel<<<gw, 256, 0, stream>>>(Wv, Wtv);

    gemm_qkv_mfma<<<1536, 256, 0, stream>>>(Ax, Wtq, Wtk, Wtv, bq, bk, bv, Q, K, Vtg);

    attn_mfma<<<1024, 256, 0, stream>>>(Q, K, Vtg, out);
}